// Round 5
// baseline (150.795 us; speedup 1.0000x reference)
//
#include <hip/hip_runtime.h>
#include <math.h>

// EulerRosenbrockModel: B=512, D=256, HID=1024, h=0.01
// out = v + 0.005 * W2 (s ⊙ (W1 v)),  s = 1-t^2, t = tanh(W1 y + b1), v = W2 t + b2
// (Neumann truncation of (I-cJ)^{-1}(I+dJ), exact to ~1e-5 — verified R1-R4.)
//
// Single persistent kernel, 256 blocks (1/CU), 3 grid barriers:
//   S1: Tb = tanh(Y@W1^T + b1)          [512x1024] bf16   (Y,W1 fp32->bf16 inline)
//   S2: Vf = Tb@W2^T + b2               [512x256]  fp32   (wave-split-K)
//   S3: Pb = (1-Tb^2) ⊙ (Vf@W1^T)       [512x1024] bf16
//   S4: OUT = Vf + 0.005*(Pb@W2^T)      [512x256]  fp32
// All MFMA 16x16x32 bf16, fp32 accumulate. Barrier counters zeroed by a
// hipMemsetAsync node (graph-capturable). 256 blocks <= resident capacity
// (LDS 36 KB -> >=4 blocks/CU), so the manual barrier cannot deadlock.

#define B_SZ 512
#define D_SZ 256
#define HID_SZ 1024

typedef short short8 __attribute__((ext_vector_type(8)));   // 8 bf16 (4 VGPRs)
typedef float f32x4 __attribute__((ext_vector_type(4)));

__device__ __forceinline__ float bf16_to_f32(unsigned short u) {
    union { unsigned int i; float f; } c; c.i = ((unsigned int)u) << 16; return c.f;
}
__device__ __forceinline__ unsigned short f32_to_bf16(float f) {
    union { float f; unsigned int i; } c; c.f = f;
    unsigned int b = c.i + 0x7FFFu + ((c.i >> 16) & 1u);   // RNE
    return (unsigned short)(b >> 16);
}
__device__ __forceinline__ uint4 pack8(float4 lo, float4 hi) {
    union { unsigned short u[8]; uint4 v; } o;
    o.u[0] = f32_to_bf16(lo.x); o.u[1] = f32_to_bf16(lo.y);
    o.u[2] = f32_to_bf16(lo.z); o.u[3] = f32_to_bf16(lo.w);
    o.u[4] = f32_to_bf16(hi.x); o.u[5] = f32_to_bf16(hi.y);
    o.u[6] = f32_to_bf16(hi.z); o.u[7] = f32_to_bf16(hi.w);
    return o.v;
}

// LDS: union of the two stage shapes (max 36352 B)
struct SMh { unsigned short A[32][72]; unsigned short B[64][72]; };
struct SMd { unsigned short A[64][72]; unsigned short B[128][72]; float r[64][34]; };
union SMu { SMh h; SMd d; };

// Two-level grid barrier: 32 leaf counters (8 blocks each) + 1 root; counters
// pre-zeroed per launch. Agent-scope atomics + threadfence for cross-XCD vis.
__device__ __forceinline__ void gbar(unsigned* c) {
    __syncthreads();                       // drains this block's vmem (vmcnt 0)
    if (threadIdx.x == 0) {
        __threadfence();                   // release: flush dirty L2 to coherent pt
        unsigned* leaf = c + (blockIdx.x & 31) * 16;   // 64B-strided lines
        unsigned* root = c + 32 * 16;
        unsigned old = __hip_atomic_fetch_add(leaf, 1u, __ATOMIC_ACQ_REL,
                                              __HIP_MEMORY_SCOPE_AGENT);
        if (old == 7u)                     // 8th arrival at this leaf
            __hip_atomic_fetch_add(root, 1u, __ATOMIC_ACQ_REL,
                                   __HIP_MEMORY_SCOPE_AGENT);
        while (__hip_atomic_load(root, __ATOMIC_ACQUIRE,
                                 __HIP_MEMORY_SCOPE_AGENT) < 32u)
            __builtin_amdgcn_s_sleep(2);
        __threadfence();                   // acquire: invalidate stale L1/L2
    }
    __syncthreads();
}

// ---- stages S1/S3: C[512,1024] = A[512,256] @ W1[1024,256]^T, tile 32x64,
// block b: bm=(b&15)*32, bn=(b>>4)*64. A and W1 are fp32, converted inline.
enum { EPI_T = 0, EPI_P = 1 };
template<int EPI>
__device__ __forceinline__
void stage_h(SMh* sm, const float* __restrict__ Afp, const float* __restrict__ W1,
             const float* __restrict__ b1, const unsigned short* __restrict__ Tin,
             unsigned short* __restrict__ Ob)
{
    const int tid = threadIdx.x;
    const int bm = (blockIdx.x & 15) * 32;
    const int bn = (blockIdx.x >> 4) * 64;
    const int wid = tid >> 6, lane = tid & 63;
    const int l16 = lane & 15, quad = lane >> 4;
    const int wm = wid >> 1, wn = wid & 1;

    f32x4 acc0 = {0.f, 0.f, 0.f, 0.f}, acc1 = {0.f, 0.f, 0.f, 0.f};
    const int arow = tid >> 3, acol = (tid & 7) * 8;

    for (int k0 = 0; k0 < 256; k0 += 64) {
        {
            const float* src = &Afp[(size_t)(bm + arow) * 256 + k0 + acol];
            float4 lo = *(const float4*)src;
            float4 hi = *(const float4*)(src + 4);
            *(uint4*)&sm->A[arow][acol] = pack8(lo, hi);
        }
#pragma unroll
        for (int r = 0; r < 2; ++r) {
            int u = r * 256 + tid;
            int brow = u >> 3, bcol = (u & 7) * 8;
            const float* src = &W1[(size_t)(bn + brow) * 256 + k0 + bcol];
            float4 lo = *(const float4*)src;
            float4 hi = *(const float4*)(src + 4);
            *(uint4*)&sm->B[brow][bcol] = pack8(lo, hi);
        }
        __syncthreads();
#pragma unroll
        for (int ks = 0; ks < 64; ks += 32) {
            short8 a   = *(const short8*)&sm->A[wm * 16 + l16][ks + quad * 8];
            short8 b0  = *(const short8*)&sm->B[wn * 32 + l16][ks + quad * 8];
            short8 b1v = *(const short8*)&sm->B[wn * 32 + 16 + l16][ks + quad * 8];
            acc0 = __builtin_amdgcn_mfma_f32_16x16x32_bf16(a, b0,  acc0, 0, 0, 0);
            acc1 = __builtin_amdgcn_mfma_f32_16x16x32_bf16(a, b1v, acc1, 0, 0, 0);
        }
        __syncthreads();
    }
    // C/D layout: col = lane&15, row = quad*4 + r   (verified R4)
#pragma unroll
    for (int t2 = 0; t2 < 2; ++t2) {
        f32x4 acc = t2 ? acc1 : acc0;
        int col = bn + wn * 32 + t2 * 16 + l16;
        float bias = 0.f;
        if constexpr (EPI == EPI_T) bias = b1[col];
#pragma unroll
        for (int r = 0; r < 4; ++r) {
            int row = bm + wm * 16 + quad * 4 + r;
            float v = acc[r];
            float o;
            if constexpr (EPI == EPI_T) {
                o = tanhf(v + bias);
            } else {
                float tt = bf16_to_f32(Tin[(size_t)row * 1024 + col]);
                o = v * (1.f - tt * tt);
            }
            Ob[(size_t)row * 1024 + col] = f32_to_bf16(o);
        }
    }
}

// ---- stages S2/S4: C[512,256] = A[512,1024] @ W2[256,1024]^T, tile 16x32,
// block b: bm=(b&31)*16, bn=(b>>5)*32. Wave w owns K chunk w*256..+256; LDS-reduce.
enum { EPI_V = 0, EPI_O = 1 };
template<int EPI>
__device__ __forceinline__
void stage_d(SMd* sm, const unsigned short* __restrict__ Ab,
             const float* __restrict__ W2, const float* __restrict__ b2,
             const float* __restrict__ Vin, float* __restrict__ Vout,
             float* __restrict__ OUT)
{
    const int tid = threadIdx.x;
    const int bm = (blockIdx.x & 31) * 16;
    const int bn = (blockIdx.x >> 5) * 32;
    const int wid = tid >> 6, lane = tid & 63;
    const int l16 = lane & 15, quad = lane >> 4;

    f32x4 acc0 = {0.f, 0.f, 0.f, 0.f}, acc1 = {0.f, 0.f, 0.f, 0.f};

    for (int i = 0; i < 4; ++i) {
#pragma unroll
        for (int r = 0; r < 2; ++r) {  // A: 4 chunks x 16 rows x 8 col-groups (bf16)
            int u = r * 256 + tid;
            int c = u >> 7, rem = u & 127;
            int row = rem >> 3, col = (rem & 7) * 8;
            *(uint4*)&sm->A[c * 16 + row][col] =
                *(const uint4*)&Ab[(size_t)(bm + row) * 1024 + c * 256 + i * 64 + col];
        }
#pragma unroll
        for (int r = 0; r < 4; ++r) {  // B: 4 chunks x 32 rows x 8 col-groups (fp32->bf16)
            int u = r * 256 + tid;
            int c = u >> 8, rem = u & 255;
            int row = rem >> 3, col = (rem & 7) * 8;
            const float* src = &W2[(size_t)(bn + row) * 1024 + c * 256 + i * 64 + col];
            float4 lo = *(const float4*)src;
            float4 hi = *(const float4*)(src + 4);
            *(uint4*)&sm->B[c * 32 + row][col] = pack8(lo, hi);
        }
        __syncthreads();
#pragma unroll
        for (int ks = 0; ks < 64; ks += 32) {
            short8 a   = *(const short8*)&sm->A[wid * 16 + l16][ks + quad * 8];
            short8 b0  = *(const short8*)&sm->B[wid * 32 + l16][ks + quad * 8];
            short8 b1v = *(const short8*)&sm->B[wid * 32 + 16 + l16][ks + quad * 8];
            acc0 = __builtin_amdgcn_mfma_f32_16x16x32_bf16(a, b0,  acc0, 0, 0, 0);
            acc1 = __builtin_amdgcn_mfma_f32_16x16x32_bf16(a, b1v, acc1, 0, 0, 0);
        }
        __syncthreads();
    }
#pragma unroll
    for (int r = 0; r < 4; ++r) {
        sm->r[wid * 16 + quad * 4 + r][l16]      = acc0[r];
        sm->r[wid * 16 + quad * 4 + r][16 + l16] = acc1[r];
    }
    __syncthreads();
    {
        int m = tid >> 4, n = (tid & 15) * 2;
        float2 s = {0.f, 0.f};
#pragma unroll
        for (int w = 0; w < 4; ++w) {
            float2 p = *(const float2*)&sm->r[w * 16 + m][n];
            s.x += p.x; s.y += p.y;
        }
        int gm = bm + m, gn = bn + n;
        size_t idx = (size_t)gm * 256 + gn;
        if constexpr (EPI == EPI_V) {
            float2 bb = *(const float2*)&b2[gn];
            float2 v = {s.x + bb.x, s.y + bb.y};
            *(float2*)&Vout[idx] = v;
        } else {
            float2 vv = *(const float2*)&Vin[idx];
            float2 o = {fmaf(0.005f, s.x, vv.x), fmaf(0.005f, s.y, vv.y)};
            *(float2*)&OUT[idx] = o;
        }
    }
}

__global__ __launch_bounds__(256)
void fused_all(const float* __restrict__ Y, const float* __restrict__ W1,
               const float* __restrict__ b1, const float* __restrict__ W2,
               const float* __restrict__ b2, float* __restrict__ OUT,
               unsigned short* __restrict__ Tb, unsigned short* __restrict__ Pb,
               float* __restrict__ Vf, unsigned* __restrict__ bar)
{
    __shared__ alignas(16) SMu sm;
    // S1: Tb = tanh(Y@W1^T + b1)
    stage_h<EPI_T>(&sm.h, Y, W1, b1, nullptr, Tb);
    gbar(bar);
    // S2: Vf = Tb@W2^T + b2
    stage_d<EPI_V>(&sm.d, Tb, W2, b2, nullptr, Vf, nullptr);
    gbar(bar + 33 * 16);
    // S3: Pb = (1-Tb^2) ⊙ (Vf@W1^T)
    stage_h<EPI_P>(&sm.h, Vf, W1, nullptr, Tb, Pb);
    gbar(bar + 2 * 33 * 16);
    // S4: OUT = Vf + 0.005*(Pb@W2^T)
    stage_d<EPI_O>(&sm.d, Pb, W2, nullptr, Vf, nullptr, OUT);
}

extern "C" void kernel_launch(void* const* d_in, const int* in_sizes, int n_in,
                              void* d_out, int out_size, void* d_ws, size_t ws_size,
                              hipStream_t stream) {
    const float* Y  = (const float*)d_in[0];  // (512, 256)
    const float* W1 = (const float*)d_in[1];  // (1024, 256)
    const float* b1 = (const float*)d_in[2];  // (1024,)
    const float* W2 = (const float*)d_in[3];  // (256, 1024)
    const float* b2 = (const float*)d_in[4];  // (256,)
    float* OUT = (float*)d_out;               // (512, 256)

    unsigned* bar = (unsigned*)d_ws;                             // 3 x 33 x 16 uints
    unsigned short* Tb = (unsigned short*)((char*)d_ws + 8192);  // [512][1024] bf16
    unsigned short* Pb = Tb + (size_t)B_SZ * HID_SZ;             // [512][1024] bf16
    float* Vf = (float*)(Pb + (size_t)B_SZ * HID_SZ);            // [512][256] fp32

    hipMemsetAsync(d_ws, 0, 3 * 33 * 16 * sizeof(unsigned), stream);
    fused_all<<<256, 256, 0, stream>>>(Y, W1, b1, W2, b2, OUT, Tb, Pb, Vf, bar);
}

// Round 6
// 92.203 us; speedup vs baseline: 1.6355x; 1.6355x over previous
//
#include <hip/hip_runtime.h>
#include <math.h>

// EulerRosenbrockModel: B=512, D=256, HID=1024, h=0.01
// out = v + 0.005 * W2 (s ⊙ (W1 v)),  s = 1-t^2, t = tanh(W1 y + b1), v = W2 t + b2
// (Neumann truncation of (I-cJ)^{-1}(I+dJ), exact to ~1e-5 — verified R1-R5.)
//
// R6 restructure: let M = W1@W2 [1024x1024], c1 = W1@b2 [1024]. Then
//   W1 v = M t + c1  and  out = W2 @ (t + 0.005*(1-t^2) ⊙ (M t + c1)) + b2.
// Serial chain is only T -> Q -> OUT (3 dispatches); M/c1 depend on weights
// only and are computed by extra blocks IN PARALLEL with T inside dispatch 1.
//   K1 (384 blocks): blocks 0-255:  Tb = tanh(Y@W1^T + b1)      [512x1024] bf16
//                    blocks 256-383: Mb = W1@W2 bf16, c1 = W1@b2 (fp32)
//   K2 (256 blocks): Qb = Tb + 0.005*(1-Tb^2) ⊙ (Tb@Mb^T + c1)  [512x1024] bf16
//   K3 (256 blocks): OUT = Qb@W2^T + b2                          [512x256] fp32
// All MFMA 16x16x32 bf16, fp32 accumulate. No grid barriers (R5 showed
// agent-scope fences cost ~30us each; dispatch boundaries are cheaper).

#define B_SZ 512
#define D_SZ 256
#define HID_SZ 1024

typedef short short8 __attribute__((ext_vector_type(8)));   // 8 bf16 (4 VGPRs)
typedef float f32x4 __attribute__((ext_vector_type(4)));

__device__ __forceinline__ float bf16_to_f32(unsigned short u) {
    union { unsigned int i; float f; } c; c.i = ((unsigned int)u) << 16; return c.f;
}
__device__ __forceinline__ unsigned short f32_to_bf16(float f) {
    union { float f; unsigned int i; } c; c.f = f;
    unsigned int b = c.i + 0x7FFFu + ((c.i >> 16) & 1u);   // RNE
    return (unsigned short)(b >> 16);
}
__device__ __forceinline__ uint4 pack8(float4 lo, float4 hi) {
    union { unsigned short u[8]; uint4 v; } o;
    o.u[0] = f32_to_bf16(lo.x); o.u[1] = f32_to_bf16(lo.y);
    o.u[2] = f32_to_bf16(lo.z); o.u[3] = f32_to_bf16(lo.w);
    o.u[4] = f32_to_bf16(hi.x); o.u[5] = f32_to_bf16(hi.y);
    o.u[6] = f32_to_bf16(hi.z); o.u[7] = f32_to_bf16(hi.w);
    return o.v;
}

// LDS shapes. K1 = union of T-part (SMh) and M-part (SMm) = 27648 B.
struct SMh { unsigned short A[32][72]; unsigned short B[64][72]; };
struct SMm { unsigned short A[64][72]; unsigned short B[128][72]; };
union SMu1 { SMh h; SMm m; };

// ======================= K1: T (256 blocks) ∥ M,c1 (128 blocks) ==============
__global__ __launch_bounds__(256)
void k1_T_and_M(const float* __restrict__ Y, const float* __restrict__ W1,
                const float* __restrict__ b1, const float* __restrict__ W2,
                const float* __restrict__ b2,
                unsigned short* __restrict__ Tb,   // [512][1024] bf16
                unsigned short* __restrict__ Mb,   // [1024][1024] bf16 (M[j][k])
                float* __restrict__ c1)            // [1024] fp32
{
    __shared__ alignas(16) SMu1 sm;
    const int tid = threadIdx.x;
    const int wid = tid >> 6, lane = tid & 63;
    const int l16 = lane & 15, quad = lane >> 4;

    if (blockIdx.x < 256) {
        // ---- T-part: T[512,1024] = tanh(Y@W1^T + b1), tile 32x64 (verified R5)
        const int bm = (blockIdx.x & 15) * 32;
        const int bn = (blockIdx.x >> 4) * 64;
        const int wm = wid >> 1, wn = wid & 1;
        f32x4 acc0 = {0.f,0.f,0.f,0.f}, acc1 = {0.f,0.f,0.f,0.f};
        const int arow = tid >> 3, acol = (tid & 7) * 8;

        for (int k0 = 0; k0 < 256; k0 += 64) {
            {
                const float* src = &Y[(size_t)(bm + arow) * 256 + k0 + acol];
                float4 lo = *(const float4*)src;
                float4 hi = *(const float4*)(src + 4);
                *(uint4*)&sm.h.A[arow][acol] = pack8(lo, hi);
            }
#pragma unroll
            for (int r = 0; r < 2; ++r) {
                int u = r * 256 + tid;
                int brow = u >> 3, bcol = (u & 7) * 8;
                const float* src = &W1[(size_t)(bn + brow) * 256 + k0 + bcol];
                float4 lo = *(const float4*)src;
                float4 hi = *(const float4*)(src + 4);
                *(uint4*)&sm.h.B[brow][bcol] = pack8(lo, hi);
            }
            __syncthreads();
#pragma unroll
            for (int ks = 0; ks < 64; ks += 32) {
                short8 a   = *(const short8*)&sm.h.A[wm * 16 + l16][ks + quad * 8];
                short8 b0  = *(const short8*)&sm.h.B[wn * 32 + l16][ks + quad * 8];
                short8 b1v = *(const short8*)&sm.h.B[wn * 32 + 16 + l16][ks + quad * 8];
                acc0 = __builtin_amdgcn_mfma_f32_16x16x32_bf16(a, b0,  acc0, 0, 0, 0);
                acc1 = __builtin_amdgcn_mfma_f32_16x16x32_bf16(a, b1v, acc1, 0, 0, 0);
            }
            __syncthreads();
        }
        // C/D layout: col = lane&15, row = quad*4 + r (verified R4)
#pragma unroll
        for (int t2 = 0; t2 < 2; ++t2) {
            f32x4 acc = t2 ? acc1 : acc0;
            int col = bn + wn * 32 + t2 * 16 + l16;
            float bias = b1[col];
#pragma unroll
            for (int r = 0; r < 4; ++r) {
                int row = bm + wm * 16 + quad * 4 + r;
                Tb[(size_t)row * 1024 + col] = f32_to_bf16(tanhf(acc[r] + bias));
            }
        }
    } else {
        // ---- M-part: M[1024,1024] = W1[1024,256] @ W2[256,1024], tile 64x128.
        // grid: 16 row-groups (j) x 8 col-groups (k). NN-GEMM: stage W2
        // transposed into LDS (Bs[k][i]) so MFMA reads are i-contiguous.
        const int blk = blockIdx.x - 256;
        const int bj = (blk & 15) * 64;
        const int bk = (blk >> 4) * 128;
        const int wm = wid >> 1, wn = wid & 1;   // 2x2 waves, wave = 32(j) x 64(k)

        // c1 = W1 @ b2 : only col-group 0 blocks (16 of them cover all j).
        if (bk == 0) {
            int j = bj + (tid >> 2);
            int q = tid & 3;
            float s = 0.f;
            const float* wrow = &W1[(size_t)j * 256 + q * 64];
#pragma unroll 16
            for (int i = 0; i < 64; ++i) s = fmaf(wrow[i], b2[q * 64 + i], s);
            s += __shfl_down(s, 2);
            s += __shfl_down(s, 1);
            if (q == 0) c1[j] = s;
        }

        f32x4 acc[2][4];
#pragma unroll
        for (int mi = 0; mi < 2; ++mi)
#pragma unroll
            for (int ni = 0; ni < 4; ++ni) acc[mi][ni] = (f32x4){0.f,0.f,0.f,0.f};

        for (int i0 = 0; i0 < 256; i0 += 64) {
            // A: W1 rows bj..+64, i-chunk 64 (fp32 -> bf16), coalesced
#pragma unroll
            for (int r = 0; r < 2; ++r) {
                int u = r * 256 + tid;
                int row = u >> 3, col = (u & 7) * 8;
                const float* src = &W1[(size_t)(bj + row) * 256 + i0 + col];
                float4 lo = *(const float4*)src;
                float4 hi = *(const float4*)(src + 4);
                *(uint4*)&sm.m.A[row][col] = pack8(lo, hi);
            }
            // B: W2[i0+i][bk + c] -> Bs[c][i] (transpose in LDS).
            // thread: i = tid&63, col-group cg = tid>>6 (32 cols each).
            {
                int i = tid & 63, cg = tid >> 6;
                const float* src = &W2[(size_t)(i0 + i) * 1024 + bk + cg * 32];
#pragma unroll
                for (int c4 = 0; c4 < 8; ++c4) {
                    float4 v = *(const float4*)(src + c4 * 4);
                    int c = cg * 32 + c4 * 4;
                    sm.m.B[c + 0][i] = f32_to_bf16(v.x);
                    sm.m.B[c + 1][i] = f32_to_bf16(v.y);
                    sm.m.B[c + 2][i] = f32_to_bf16(v.z);
                    sm.m.B[c + 3][i] = f32_to_bf16(v.w);
                }
            }
            __syncthreads();
#pragma unroll
            for (int ks = 0; ks < 64; ks += 32) {
#pragma unroll
                for (int mi = 0; mi < 2; ++mi) {
                    short8 a = *(const short8*)&sm.m.A[wm * 32 + mi * 16 + l16][ks + quad * 8];
#pragma unroll
                    for (int ni = 0; ni < 4; ++ni) {
                        short8 b = *(const short8*)&sm.m.B[wn * 64 + ni * 16 + l16][ks + quad * 8];
                        acc[mi][ni] = __builtin_amdgcn_mfma_f32_16x16x32_bf16(a, b, acc[mi][ni], 0, 0, 0);
                    }
                }
            }
            __syncthreads();
        }
#pragma unroll
        for (int mi = 0; mi < 2; ++mi)
#pragma unroll
            for (int ni = 0; ni < 4; ++ni) {
                int col = bk + wn * 64 + ni * 16 + l16;
#pragma unroll
                for (int r = 0; r < 4; ++r) {
                    int row = bj + wm * 32 + mi * 16 + quad * 4 + r;
                    Mb[(size_t)row * 1024 + col] = f32_to_bf16(acc[mi][ni][r]);
                }
            }
    }
}

// ======================= K2: Q = T + 0.005*(1-T^2)⊙(T@M^T + c1) ==============
// M=512, N=1024, K=1024, tile 32x64, grid (16,16)=256 blocks.
__global__ __launch_bounds__(256)
void k2_Q(const unsigned short* __restrict__ Tb, const unsigned short* __restrict__ Mb,
          const float* __restrict__ c1, unsigned short* __restrict__ Qb)
{
    __shared__ alignas(16) SMh sm;
    const int tid = threadIdx.x;
    const int bm = blockIdx.x * 32;
    const int bn = blockIdx.y * 64;
    const int wid = tid >> 6, lane = tid & 63;
    const int l16 = lane & 15, quad = lane >> 4;
    const int wm = wid >> 1, wn = wid & 1;

    f32x4 acc0 = {0.f,0.f,0.f,0.f}, acc1 = {0.f,0.f,0.f,0.f};
    const int arow = tid >> 3, acol = (tid & 7) * 8;

    for (int k0 = 0; k0 < 1024; k0 += 64) {
        *(uint4*)&sm.A[arow][acol] = *(const uint4*)&Tb[(size_t)(bm + arow) * 1024 + k0 + acol];
#pragma unroll
        for (int r = 0; r < 2; ++r) {
            int u = r * 256 + tid;
            int brow = u >> 3, bcol = (u & 7) * 8;
            *(uint4*)&sm.B[brow][bcol] = *(const uint4*)&Mb[(size_t)(bn + brow) * 1024 + k0 + bcol];
        }
        __syncthreads();
#pragma unroll
        for (int ks = 0; ks < 64; ks += 32) {
            short8 a   = *(const short8*)&sm.A[wm * 16 + l16][ks + quad * 8];
            short8 b0  = *(const short8*)&sm.B[wn * 32 + l16][ks + quad * 8];
            short8 b1v = *(const short8*)&sm.B[wn * 32 + 16 + l16][ks + quad * 8];
            acc0 = __builtin_amdgcn_mfma_f32_16x16x32_bf16(a, b0,  acc0, 0, 0, 0);
            acc1 = __builtin_amdgcn_mfma_f32_16x16x32_bf16(a, b1v, acc1, 0, 0, 0);
        }
        __syncthreads();
    }
#pragma unroll
    for (int t2 = 0; t2 < 2; ++t2) {
        f32x4 acc = t2 ? acc1 : acc0;
        int col = bn + wn * 32 + t2 * 16 + l16;
        float cc = c1[col];
#pragma unroll
        for (int r = 0; r < 4; ++r) {
            int row = bm + wm * 16 + quad * 4 + r;
            float tt = bf16_to_f32(Tb[(size_t)row * 1024 + col]);
            float q = tt + 0.005f * (1.f - tt * tt) * (acc[r] + cc);
            Qb[(size_t)row * 1024 + col] = f32_to_bf16(q);
        }
    }
}

// ======================= K3: OUT = Q@W2^T + b2 ==============================
// M=512, N=256, K=1024, tile 16x32, grid (32,8)=256, wave-split-K (verified R4/R5).
__global__ __launch_bounds__(256)
void k3_out(const unsigned short* __restrict__ Qb, const float* __restrict__ W2,
            const float* __restrict__ b2, float* __restrict__ OUT)
{
    __shared__ alignas(16) unsigned short As[64][72];
    __shared__ alignas(16) unsigned short Bs[128][72];
    __shared__ alignas(16) float red[64][34];
    const int tid = threadIdx.x;
    const int bm = blockIdx.x * 16;
    const int bn = blockIdx.y * 32;
    const int wid = tid >> 6, lane = tid & 63;
    const int l16 = lane & 15, quad = lane >> 4;

    f32x4 acc0 = {0.f,0.f,0.f,0.f}, acc1 = {0.f,0.f,0.f,0.f};

    for (int i = 0; i < 4; ++i) {
#pragma unroll
        for (int r = 0; r < 2; ++r) {  // A: 4 chunks x 16 rows x 8 col-groups (bf16)
            int u = r * 256 + tid;
            int c = u >> 7, rem = u & 127;
            int row = rem >> 3, col = (rem & 7) * 8;
            *(uint4*)&As[c * 16 + row][col] =
                *(const uint4*)&Qb[(size_t)(bm + row) * 1024 + c * 256 + i * 64 + col];
        }
#pragma unroll
        for (int r = 0; r < 4; ++r) {  // B: 4 chunks x 32 rows x 8 col-groups (fp32->bf16)
            int u = r * 256 + tid;
            int c = u >> 8, rem = u & 255;
            int row = rem >> 3, col = (rem & 7) * 8;
            const float* src = &W2[(size_t)(bn + row) * 1024 + c * 256 + i * 64 + col];
            float4 lo = *(const float4*)src;
            float4 hi = *(const float4*)(src + 4);
            *(uint4*)&Bs[c * 32 + row][col] = pack8(lo, hi);
        }
        __syncthreads();
#pragma unroll
        for (int ks = 0; ks < 64; ks += 32) {
            short8 a   = *(const short8*)&As[wid * 16 + l16][ks + quad * 8];
            short8 b0  = *(const short8*)&Bs[wid * 32 + l16][ks + quad * 8];
            short8 b1v = *(const short8*)&Bs[wid * 32 + 16 + l16][ks + quad * 8];
            acc0 = __builtin_amdgcn_mfma_f32_16x16x32_bf16(a, b0,  acc0, 0, 0, 0);
            acc1 = __builtin_amdgcn_mfma_f32_16x16x32_bf16(a, b1v, acc1, 0, 0, 0);
        }
        __syncthreads();
    }
#pragma unroll
    for (int r = 0; r < 4; ++r) {
        red[wid * 16 + quad * 4 + r][l16]      = acc0[r];
        red[wid * 16 + quad * 4 + r][16 + l16] = acc1[r];
    }
    __syncthreads();
    {
        int m = tid >> 4, n = (tid & 15) * 2;
        float2 s = {0.f, 0.f};
#pragma unroll
        for (int w = 0; w < 4; ++w) {
            float2 p = *(const float2*)&red[w * 16 + m][n];
            s.x += p.x; s.y += p.y;
        }
        int gm = bm + m, gn = bn + n;
        float2 bb = *(const float2*)&b2[gn];
        float2 o = {s.x + bb.x, s.y + bb.y};
        *(float2*)&OUT[(size_t)gm * 256 + gn] = o;
    }
}

extern "C" void kernel_launch(void* const* d_in, const int* in_sizes, int n_in,
                              void* d_out, int out_size, void* d_ws, size_t ws_size,
                              hipStream_t stream) {
    const float* Y  = (const float*)d_in[0];  // (512, 256)
    const float* W1 = (const float*)d_in[1];  // (1024, 256)
    const float* b1 = (const float*)d_in[2];  // (1024,)
    const float* W2 = (const float*)d_in[3];  // (256, 1024)
    const float* b2 = (const float*)d_in[4];  // (256,)
    float* OUT = (float*)d_out;               // (512, 256)

    unsigned short* Tb = (unsigned short*)d_ws;                  // [512][1024] bf16, 1 MB
    unsigned short* Qb = Tb + (size_t)B_SZ * HID_SZ;             // [512][1024] bf16, 1 MB
    unsigned short* Mb = Qb + (size_t)B_SZ * HID_SZ;             // [1024][1024] bf16, 2 MB
    float* c1 = (float*)(Mb + (size_t)HID_SZ * HID_SZ);          // [1024] fp32

    k1_T_and_M<<<384, 256, 0, stream>>>(Y, W1, b1, W2, b2, Tb, Mb, c1);
    k2_Q<<<dim3(16, 16), 256, 0, stream>>>(Tb, Mb, c1, Qb);
    k3_out<<<dim3(32, 8), 256, 0, stream>>>(Qb, W2, b2, OUT);
}

// Round 7
// 78.391 us; speedup vs baseline: 1.9236x; 1.1762x over previous
//
#include <hip/hip_runtime.h>
#include <math.h>

// EulerRosenbrockModel: B=512, D=256, HID=1024, h=0.01
// out = v + 0.005 * W2 (s ⊙ (W1 v)),  s = 1-t^2, t = tanh(W1 y + b1), v = W2 t + b2
// (Neumann truncation of (I-cJ)^{-1}(I+dJ), exact to ~1e-5 — verified R1-R6.)
//
// R7: R4's minimal-FLOP chain (1.07 GF), 4 dispatches, 256 blocks (1/CU) each:
//   K1: Tb = tanh(Y@W1^T + b1)            [512x1024] bf16  (Y,W1 fp32->bf16 inline)
//   K2: Vf = Tb@W2^T + b2 (fp32) + Vb bf16 [512x256]       (wave-split-K)
//   K3: Pb = (1-Tb^2) ⊙ (Vb@W1^T)         [512x1024] bf16
//   K4: OUT = Vf + 0.005*(Pb@W2^T)        [512x256]  fp32
// vs R4: prep dispatch removed (inline conversion, pattern verified R5) and
// monolithic K-panel staging (1 sync in gemm_h vs 8; all global loads issue
// before a single wait). No grid barriers (R5: ~30us each), no M-trick (R6:
// +1.6 GF net loss).

#define B_SZ 512
#define D_SZ 256
#define HID_SZ 1024

typedef short short8 __attribute__((ext_vector_type(8)));   // 8 bf16 (4 VGPRs)
typedef float f32x4 __attribute__((ext_vector_type(4)));

__device__ __forceinline__ float bf16_to_f32(unsigned short u) {
    union { unsigned int i; float f; } c; c.i = ((unsigned int)u) << 16; return c.f;
}
__device__ __forceinline__ unsigned short f32_to_bf16(float f) {
    union { float f; unsigned int i; } c; c.f = f;
    unsigned int b = c.i + 0x7FFFu + ((c.i >> 16) & 1u);   // RNE
    return (unsigned short)(b >> 16);
}
__device__ __forceinline__ uint4 pack8(float4 lo, float4 hi) {
    union { unsigned short u[8]; uint4 v; } o;
    o.u[0] = f32_to_bf16(lo.x); o.u[1] = f32_to_bf16(lo.y);
    o.u[2] = f32_to_bf16(lo.z); o.u[3] = f32_to_bf16(lo.w);
    o.u[4] = f32_to_bf16(hi.x); o.u[5] = f32_to_bf16(hi.y);
    o.u[6] = f32_to_bf16(hi.z); o.u[7] = f32_to_bf16(hi.w);
    return o.v;
}

// ==== K1/K3: C[512,1024] = A[512,256] @ W1[1024,256]^T, tile 32x64, 256 blocks.
// Whole K=256 panel staged once -> single __syncthreads before MFMA.
enum { EPI_T = 0, EPI_P = 1 };
template<int EPI>
__global__ __launch_bounds__(256)
void gemm_h(const float* __restrict__ Afp,          // EPI_T: Y fp32
            const unsigned short* __restrict__ Abf, // EPI_P: Vb bf16
            const float* __restrict__ W1,
            const float* __restrict__ b1,
            const unsigned short* __restrict__ Tin, // EPI_P: Tb
            unsigned short* __restrict__ Ob)        // Tb or Pb
{
    __shared__ alignas(16) unsigned short As[32][264];  // 16.9 KB (stride 528B: 4-bank shift)
    __shared__ alignas(16) unsigned short Bs[64][264];  // 33.8 KB
    const int tid = threadIdx.x;
    const int bm = (blockIdx.x & 15) * 32;
    const int bn = (blockIdx.x >> 4) * 64;
    const int wid = tid >> 6, lane = tid & 63;
    const int l16 = lane & 15, quad = lane >> 4;
    const int wm = wid >> 1, wn = wid & 1;

    // stage A: 32 rows x 256 k (4 units of 8 elems per thread)
#pragma unroll
    for (int l = 0; l < 4; ++l) {
        int q = l * 256 + tid;
        int row = q >> 5, col = (q & 31) * 8;
        if constexpr (EPI == EPI_T) {
            const float* src = &Afp[(size_t)(bm + row) * 256 + col];
            float4 lo = *(const float4*)src;
            float4 hi = *(const float4*)(src + 4);
            *(uint4*)&As[row][col] = pack8(lo, hi);
        } else {
            *(uint4*)&As[row][col] = *(const uint4*)&Abf[(size_t)(bm + row) * 256 + col];
        }
    }
    // stage B: 64 rows x 256 k (8 units per thread), fp32 W1 -> bf16
#pragma unroll
    for (int l = 0; l < 8; ++l) {
        int q = l * 256 + tid;
        int row = q >> 5, col = (q & 31) * 8;
        const float* src = &W1[(size_t)(bn + row) * 256 + col];
        float4 lo = *(const float4*)src;
        float4 hi = *(const float4*)(src + 4);
        *(uint4*)&Bs[row][col] = pack8(lo, hi);
    }
    __syncthreads();

    f32x4 acc0 = {0.f,0.f,0.f,0.f}, acc1 = {0.f,0.f,0.f,0.f};
#pragma unroll
    for (int ks = 0; ks < 256; ks += 32) {
        short8 a   = *(const short8*)&As[wm * 16 + l16][ks + quad * 8];
        short8 b0  = *(const short8*)&Bs[wn * 32 + l16][ks + quad * 8];
        short8 b1v = *(const short8*)&Bs[wn * 32 + 16 + l16][ks + quad * 8];
        acc0 = __builtin_amdgcn_mfma_f32_16x16x32_bf16(a, b0,  acc0, 0, 0, 0);
        acc1 = __builtin_amdgcn_mfma_f32_16x16x32_bf16(a, b1v, acc1, 0, 0, 0);
    }
    // C/D layout: col = lane&15, row = quad*4 + r (verified R4-R6)
#pragma unroll
    for (int t2 = 0; t2 < 2; ++t2) {
        f32x4 acc = t2 ? acc1 : acc0;
        int col = bn + wn * 32 + t2 * 16 + l16;
        float bias = 0.f;
        if constexpr (EPI == EPI_T) bias = b1[col];
#pragma unroll
        for (int r = 0; r < 4; ++r) {
            int row = bm + wm * 16 + quad * 4 + r;
            float v = acc[r];
            float o;
            if constexpr (EPI == EPI_T) {
                o = tanhf(v + bias);
            } else {
                float tt = bf16_to_f32(Tin[(size_t)row * 1024 + col]);
                o = v * (1.f - tt * tt);
            }
            Ob[(size_t)row * 1024 + col] = f32_to_bf16(o);
        }
    }
}

// ==== K2/K4: C[512,256] = A[512,1024] @ W2[256,1024]^T, tile 16x32, 256 blocks.
// Wave w owns K chunk w*256..+256; K staged in 2 phases of 512 (wave slice 128/phase).
enum { EPI_V = 0, EPI_O = 1 };
template<int EPI>
__global__ __launch_bounds__(256)
void gemm_d(const unsigned short* __restrict__ Ab,  // Tb or Pb, [512][1024] bf16
            const float* __restrict__ W2,           // [256][1024] fp32
            const float* __restrict__ b2,
            const float* __restrict__ Vin,          // EPI_O
            float* __restrict__ Vf_out,             // EPI_V
            unsigned short* __restrict__ Vb_out,    // EPI_V
            float* __restrict__ OUT)                // EPI_O
{
    __shared__ alignas(16) unsigned short As[16][520];  // 16.6 KB
    __shared__ alignas(16) unsigned short Bs[32][520];  // 33.3 KB
    __shared__ alignas(16) float red[64][34];           // 8.7 KB  (total 58.6 KB)
    const int tid = threadIdx.x;
    const int bm = (blockIdx.x & 31) * 16;
    const int bn = (blockIdx.x >> 5) * 32;
    const int wid = tid >> 6, lane = tid & 63;
    const int l16 = lane & 15, quad = lane >> 4;
    const int woff = wid * 128;   // wave's in-phase LDS k-offset

    f32x4 acc0 = {0.f,0.f,0.f,0.f}, acc1 = {0.f,0.f,0.f,0.f};

#pragma unroll
    for (int p = 0; p < 2; ++p) {
        // stage A: 16 rows x 512 k bf16 (4 units/thread, direct copy)
#pragma unroll
        for (int l = 0; l < 4; ++l) {
            int q = l * 256 + tid;
            int row = q >> 6, col = (q & 63) * 8;
            *(uint4*)&As[row][col] =
                *(const uint4*)&Ab[(size_t)(bm + row) * 1024 + p * 512 + col];
        }
        // stage B: 32 rows x 512 k, fp32 W2 -> bf16 (8 units/thread)
#pragma unroll
        for (int l = 0; l < 8; ++l) {
            int q = l * 256 + tid;
            int row = q >> 6, col = (q & 63) * 8;
            const float* src = &W2[(size_t)(bn + row) * 1024 + p * 512 + col];
            float4 lo = *(const float4*)src;
            float4 hi = *(const float4*)(src + 4);
            *(uint4*)&Bs[row][col] = pack8(lo, hi);
        }
        __syncthreads();
#pragma unroll
        for (int ks = 0; ks < 128; ks += 32) {
            short8 a   = *(const short8*)&As[l16][woff + ks + quad * 8];
            short8 b0  = *(const short8*)&Bs[l16][woff + ks + quad * 8];
            short8 b1v = *(const short8*)&Bs[16 + l16][woff + ks + quad * 8];
            acc0 = __builtin_amdgcn_mfma_f32_16x16x32_bf16(a, b0,  acc0, 0, 0, 0);
            acc1 = __builtin_amdgcn_mfma_f32_16x16x32_bf16(a, b1v, acc1, 0, 0, 0);
        }
        __syncthreads();
    }
    // cross-wave K reduction via LDS (verified R4-R6)
#pragma unroll
    for (int r = 0; r < 4; ++r) {
        red[wid * 16 + quad * 4 + r][l16]      = acc0[r];
        red[wid * 16 + quad * 4 + r][16 + l16] = acc1[r];
    }
    __syncthreads();
    {
        int m = tid >> 4, n = (tid & 15) * 2;
        float2 s = {0.f, 0.f};
#pragma unroll
        for (int w = 0; w < 4; ++w) {
            float2 pv = *(const float2*)&red[w * 16 + m][n];
            s.x += pv.x; s.y += pv.y;
        }
        int gm = bm + m, gn = bn + n;
        size_t idx = (size_t)gm * 256 + gn;
        if constexpr (EPI == EPI_V) {
            float2 bb = *(const float2*)&b2[gn];
            float2 v = {s.x + bb.x, s.y + bb.y};
            *(float2*)&Vf_out[idx] = v;
            Vb_out[idx]     = f32_to_bf16(v.x);
            Vb_out[idx + 1] = f32_to_bf16(v.y);
        } else {
            float2 vv = *(const float2*)&Vin[idx];
            float2 o = {fmaf(0.005f, s.x, vv.x), fmaf(0.005f, s.y, vv.y)};
            *(float2*)&OUT[idx] = o;
        }
    }
}

extern "C" void kernel_launch(void* const* d_in, const int* in_sizes, int n_in,
                              void* d_out, int out_size, void* d_ws, size_t ws_size,
                              hipStream_t stream) {
    const float* Y  = (const float*)d_in[0];  // (512, 256)
    const float* W1 = (const float*)d_in[1];  // (1024, 256)
    const float* b1 = (const float*)d_in[2];  // (1024,)
    const float* W2 = (const float*)d_in[3];  // (256, 1024)
    const float* b2 = (const float*)d_in[4];  // (256,)
    float* OUT = (float*)d_out;               // (512, 256)

    unsigned short* Tb = (unsigned short*)d_ws;        // [512][1024] bf16, 1 MB
    unsigned short* Pb = Tb + (size_t)B_SZ * HID_SZ;   // [512][1024] bf16, 1 MB
    unsigned short* Vb = Pb + (size_t)B_SZ * HID_SZ;   // [512][256]  bf16, 256 KB
    float*          Vf = (float*)(Vb + (size_t)B_SZ * D_SZ);  // [512][256] fp32

    gemm_h<EPI_T><<<256, 256, 0, stream>>>(Y, nullptr, W1, b1, nullptr, Tb);
    gemm_d<EPI_V><<<256, 256, 0, stream>>>(Tb, W2, b2, nullptr, Vf, Vb, nullptr);
    gemm_h<EPI_P><<<256, 256, 0, stream>>>(nullptr, Vb, W1, nullptr, Tb, Pb);
    gemm_d<EPI_O><<<256, 256, 0, stream>>>(Pb, W2, nullptr, Vf, nullptr, nullptr, OUT);
}